// Round 11
// baseline (383.645 us; speedup 1.0000x reference)
//
#include <hip/hip_runtime.h>
#include <hip/hip_bf16.h>

#define N_NODES 16384
#define NEDGE   1048576

typedef __attribute__((ext_vector_type(4))) float f32x4;
typedef __attribute__((ext_vector_type(4))) unsigned u32x4;
typedef __attribute__((ext_vector_type(8))) short bf16x8;
typedef unsigned short u16;

__device__ __forceinline__ short f2bf(float f) {
  union { float f; unsigned u; } v; v.f = f;
  unsigned r = v.u + 0x7FFFu + ((v.u >> 16) & 1u);  // RNE
  return (short)(r >> 16);
}
__device__ __forceinline__ unsigned pk2(float lo, float hi) {
  __hip_bfloat162 h = __float22bfloat162_rn(make_float2(lo, hi));
  return *reinterpret_cast<unsigned*>(&h);
}
__device__ __forceinline__ bf16x8 cvt8(f32x4 a, f32x4 b) {
  u32x4 u;
  u[0] = pk2(a[0], a[1]); u[1] = pk2(a[2], a[3]);
  u[2] = pk2(b[0], b[1]); u[3] = pk2(b[2], b[3]);
  return __builtin_bit_cast(bf16x8, u);
}
__device__ __forceinline__ float red16(float v) {
  v += __shfl_xor(v, 1); v += __shfl_xor(v, 2);
  v += __shfl_xor(v, 4); v += __shfl_xor(v, 8);
  return v;
}
__device__ __forceinline__ float red64(float v) {
  v += __shfl_xor(v, 1); v += __shfl_xor(v, 2); v += __shfl_xor(v, 4);
  v += __shfl_xor(v, 8); v += __shfl_xor(v, 16); v += __shfl_xor(v, 32);
  return v;
}
__device__ __forceinline__ float lrelu(float x){ return x >= 0.f ? x : 0.2f*x; }

// ---------------------------------------------------------------------------
// Prep: pack x / fc1_w / gat_w into MFMA B-fragment order (bf16), compute the
// six style gamma/beta vectors. Blocks >= 531 run the edge histogram
// (cnt pre-zeroed by hipMemsetAsync before this kernel).
// gb layout: g1[64] be1[64] g2[256] be2[256] g3[64] be3[64]
// ---------------------------------------------------------------------------
__global__ __launch_bounds__(256) void k_prep(
    const float* __restrict__ x, const float* __restrict__ style,
    const float* __restrict__ fc1_w, const float* __restrict__ gat_w,
    const float* __restrict__ a1w1, const float* __restrict__ a1b1,
    const float* __restrict__ a1w2, const float* __restrict__ a1b2,
    const float* __restrict__ a2w1, const float* __restrict__ a2b1,
    const float* __restrict__ a2w2, const float* __restrict__ a2b2,
    const float* __restrict__ a3w1, const float* __restrict__ a3b1,
    const float* __restrict__ a3w2, const float* __restrict__ a3b2,
    u16* __restrict__ xpk, u16* __restrict__ fc1pk, u16* __restrict__ gatpk,
    float* __restrict__ gb, const int* __restrict__ dst, int* __restrict__ cnt)
{
  if (blockIdx.x >= 531) {            // fused histogram: 1024 blocks
    int t = ((blockIdx.x - 531) << 8) + threadIdx.x;
    #pragma unroll
    for (int i = 0; i < 4; ++i) atomicAdd(&cnt[dst[t + i*262144]], 1);
    return;
  }
  int tid = blockIdx.x * 256 + threadIdx.x;
  if (tid < 131072) {                 // xpk: 512 ktiles x 4 ntiles x 64 lanes
    int lane = tid & 63;
    int kt = tid >> 8, nt = (tid >> 6) & 3;
    int k0 = kt*32 + (lane>>4)*8, c = nt*16 + (lane&15);
    bf16x8 o;
    #pragma unroll
    for (int j = 0; j < 8; ++j) o[j] = f2bf(x[(size_t)(k0+j)*64 + c]);
    ((bf16x8*)xpk)[tid] = o;
  } else if (tid < 133120) {          // fc1pk: 2 ktiles x 16 ntiles x 64 lanes
    int t2 = tid - 131072;
    int lane = t2 & 63, kt = t2 >> 10, nt = (t2 >> 6) & 15;
    int k0 = kt*32 + (lane>>4)*8, c = nt*16 + (lane&15);
    bf16x8 o;
    #pragma unroll
    for (int j = 0; j < 8; ++j) o[j] = f2bf(fc1_w[(size_t)c*64 + k0 + j]);
    ((bf16x8*)fc1pk)[t2] = o;
  } else if (tid < 135168) {          // gatpk: 8 ktiles x 4 ntiles x 64 lanes
    int t3 = tid - 133120;
    int lane = t3 & 63, kt = t3 >> 8, nt = (t3 >> 6) & 3;
    int k0 = kt*32 + (lane>>4)*8, c = nt*16 + (lane&15);
    bf16x8 o;
    #pragma unroll
    for (int j = 0; j < 8; ++j) o[j] = f2bf(gat_w[(size_t)c*256 + k0 + j]);
    ((bf16x8*)gatpk)[t3] = o;
  } else if (tid < 135936) {          // gamma/beta dots
    int t4 = tid - 135168;
    const float* wp; const float* bp; float* op; int d;
    if (t4 < 64)       { wp=a1w1; bp=a1b1; op=gb;       d=t4; }
    else if (t4 < 128) { wp=a1w2; bp=a1b2; op=gb+64;    d=t4-64; }
    else if (t4 < 384) { wp=a2w1; bp=a2b1; op=gb+128;   d=t4-128; }
    else if (t4 < 640) { wp=a2w2; bp=a2b2; op=gb+384;   d=t4-384; }
    else if (t4 < 704) { wp=a3w1; bp=a3b1; op=gb+640;   d=t4-640; }
    else               { wp=a3w2; bp=a3b2; op=gb+704;   d=t4-704; }
    float s = bp[d];
    for (int k = 0; k < 64; ++k) s += wp[(size_t)d*64 + k] * style[k];
    op[d] = s;
  }
}

// ---------------------------------------------------------------------------
// K1: fused gemm1 + BN2 + leaky + adain1 + gemm2 + colstats.
// LDS-staged W-stream, 3-deep register pipeline (P/Q sets, unroll-2):
// per iter {ds_write chunk it+1 (loads 2 iters old -> no stall);
//           issue loads chunk it+3; compute chunk it; barrier}.
// Contiguous 1KB/instruction loads, XOR-swizzled 16B units.
// Wave w owns n-tile w. Block 1024 = counting-sort scan.
// ---------------------------------------------------------------------------
__global__ __launch_bounds__(256, 4) void k_gemm12(
    const float* __restrict__ W, const u16* __restrict__ xpk,
    const float* __restrict__ trs_b, const float* __restrict__ bn2_g,
    const float* __restrict__ bn2_b, const float* __restrict__ g1,
    const float* __restrict__ be1,
    const u16* __restrict__ fc1pk, const float* __restrict__ fc1_b,
    float* __restrict__ H3, float* __restrict__ colsum, float* __restrict__ colsq,
    const int* __restrict__ cnt, int* __restrict__ off, int* __restrict__ cur)
{
  if (blockIdx.x == 1024) {           // fused scan (counting-sort offsets)
    __shared__ int ps[256];
    int t = threadIdx.x;
    int base = t * 64;
    int s = 0;
    for (int i = 0; i < 64; ++i) s += cnt[base + i];
    ps[t] = s;
    __syncthreads();
    for (int d = 1; d < 256; d <<= 1) {
      int v = (t >= d) ? ps[t - d] : 0;
      __syncthreads();
      ps[t] += v;
      __syncthreads();
    }
    int run = ps[t] - s;
    for (int i = 0; i < 64; ++i) {
      off[base + i] = run; cur[base + i] = run;
      run += cnt[base + i];
    }
    return;
  }
  const int tid  = threadIdx.x;
  const int lane = tid & 63;
  const int wv   = tid >> 6;
  const int jb   = blockIdx.x << 4;
  const int c0   = lane & 15, kg = lane >> 4;
  const int sw   = c0 & 7;

  __shared__ __align__(16) float lbuf[2][4096];   // [buf][row*256 + unit16B*4]
  __shared__ float h2t[16 * 68];

  // staging: thread covers rows wv+4i (i=0..3), 16B-unit `lane` of each 1KB chunk
  const float* gsrc[4];
  int ldst[4];
  #pragma unroll
  for (int i = 0; i < 4; ++i) {
    int r = wv + (i << 2);
    gsrc[i] = W + (size_t)(jb + r) * 16384 + (size_t)((lane ^ (r & 7)) << 2);
    ldst[i] = ((r << 6) + lane) << 2;
  }

  const int it0 = blockIdx.x & 63;               // K start-phase rotation
  f32x4 z = {0.f,0.f,0.f,0.f};
  f32x4 acc = z;
  f32x4 P[4], Q[4];

  {   // prologue: stage chunk 0 directly; P <- chunk 1, Q <- chunk 2
    int kk0 = it0 << 8;
    #pragma unroll
    for (int i = 0; i < 4; ++i) {
      f32x4 v = __builtin_nontemporal_load((const f32x4*)(gsrc[i] + kk0));
      *(f32x4*)&lbuf[0][ldst[i]] = v;
    }
    int kk1 = ((it0 + 1) & 63) << 8;
    #pragma unroll
    for (int i = 0; i < 4; ++i)
      P[i] = __builtin_nontemporal_load((const f32x4*)(gsrc[i] + kk1));
    int kk2 = ((it0 + 2) & 63) << 8;
    #pragma unroll
    for (int i = 0; i < 4; ++i)
      Q[i] = __builtin_nontemporal_load((const f32x4*)(gsrc[i] + kk2));
  }
  __syncthreads();

  const bf16x8* xb = ((const bf16x8*)xpk) + (wv << 6) + lane;

#define G1_BODY(ITX, R) do {                                                 \
    const int it_ = (ITX);                                                   \
    /* 1) stage chunk it_+1 from R (loads issued 2 iters ago) */             \
    {                                                                        \
      float* lo_ = lbuf[(it_ + 1) & 1];                                      \
      _Pragma("unroll")                                                      \
      for (int i = 0; i < 4; ++i) *(f32x4*)&lo_[ldst[i]] = R[i];             \
    }                                                                        \
    /* 2) refill R with chunk it_+3 */                                       \
    if (it_ <= 60) {                                                         \
      int kk_ = ((it_ + 3 + it0) & 63) << 8;                                 \
      _Pragma("unroll")                                                      \
      for (int i = 0; i < 4; ++i)                                            \
        R[i] = __builtin_nontemporal_load((const f32x4*)(gsrc[i] + kk_));    \
    }                                                                        \
    /* 3) compute chunk it_ from lbuf[it_&1] */                              \
    {                                                                        \
      int ktg0_ = ((it_ + it0) & 63) << 3;                                   \
      const float* lb_ = lbuf[it_ & 1] + (c0 << 8);                          \
      const bf16x8* bp_ = xb + (size_t)ktg0_ * 256;                          \
      _Pragma("unroll")                                                      \
      for (int kt = 0; kt < 8; ++kt) {                                       \
        int u0_ = (kt << 3) + (kg << 1);                                     \
        f32x4 a0 = *(const f32x4*)(lb_ + ((u0_ ^ sw) << 2));                 \
        f32x4 a1 = *(const f32x4*)(lb_ + (((u0_ + 1) ^ sw) << 2));           \
        bf16x8 b = bp_[(size_t)kt << 8];                                     \
        acc = __builtin_amdgcn_mfma_f32_16x16x32_bf16(cvt8(a0, a1), b, acc, 0,0,0); \
      }                                                                      \
    }                                                                        \
    __syncthreads();                                                         \
  } while (0)

  for (int i2 = 0; i2 < 31; ++i2) {
    G1_BODY(2 * i2,     P);
    G1_BODY(2 * i2 + 1, Q);
  }
  G1_BODY(62, P);
  {   // epilogue: compute chunk 63 (already staged), no write/issue
    int ktg0 = ((63 + it0) & 63) << 3;
    const float* lb = lbuf[1] + (c0 << 8);
    const bf16x8* bp = xb + (size_t)ktg0 * 256;
    #pragma unroll
    for (int kt = 0; kt < 8; ++kt) {
      int u0 = (kt << 3) + (kg << 1);
      f32x4 a0 = *(const f32x4*)(lb + ((u0 ^ sw) << 2));
      f32x4 a1 = *(const f32x4*)(lb + (((u0 + 1) ^ sw) << 2));
      bf16x8 b = bp[(size_t)kt << 8];
      acc = __builtin_amdgcn_mfma_f32_16x16x32_bf16(cvt8(a0, a1), b, acc, 0,0,0);
    }
  }
#undef G1_BODY
  __syncthreads();

  // dump acc tile: rows kg*4+i (block-local), cols wv*16+c0
  #pragma unroll
  for (int i = 0; i < 4; ++i)
    h2t[((kg << 2) + i) * 68 + (wv << 4) + c0] = acc[i];
  __syncthreads();

  // BN2 + leaky + adain1, row-parallel: wave wv handles rows 4wv..4wv+3
  #pragma unroll
  for (int i = 0; i < 4; ++i) {
    int jr = (wv << 2) + i;
    int j  = jb + jr;
    float v = h2t[jr * 68 + lane] + trs_b[j];
    float s = red64(v), q = red64(v * v);
    float mean = s * 0.015625f;
    float var  = q * 0.015625f - mean * mean;
    float inv  = rsqrtf(var + 1e-5f) * bn2_g[j];
    v = lrelu((v - mean) * inv + bn2_b[j]);
    s = red64(v); q = red64(v * v);
    mean = s * 0.015625f;
    var  = q * 0.015625f - mean * mean;
    float sd = sqrtf(fmaxf(var, 0.f) * (64.f / 63.f));
    float id = 1.f / (sd + 1e-8f);
    h2t[jr * 68 + lane] = g1[lane] * (v - mean) * id + be1[lane];
  }
  __syncthreads();

  // gemm2 on the LDS tile: H3 tile = h2t @ fc1_w.T + colstats
  const float* ha = h2t + c0 * 68 + (kg << 3);
  bf16x8 a0 = cvt8(*(const f32x4*)ha,        *(const f32x4*)(ha+4));
  bf16x8 a1 = cvt8(*(const f32x4*)(ha+32),   *(const f32x4*)(ha+36));
  const bf16x8* fpv = ((const bf16x8*)fc1pk) + lane;
  f32x4 acc2[4] = {z,z,z,z};
  #pragma unroll
  for (int q = 0; q < 4; ++q) {
    int nt = (wv << 2) | q;
    acc2[q] = __builtin_amdgcn_mfma_f32_16x16x32_bf16(a0, fpv[nt*64],      acc2[q], 0,0,0);
    acc2[q] = __builtin_amdgcn_mfma_f32_16x16x32_bf16(a1, fpv[(16+nt)*64], acc2[q], 0,0,0);
  }
  #pragma unroll
  for (int q = 0; q < 4; ++q) {
    int c = (((wv << 2) | q) << 4) + c0;
    float bias = fc1_b[c];
    float cs = 0.f, cq = 0.f;
    #pragma unroll
    for (int r = 0; r < 4; ++r) {
      float v = acc2[q][r] + bias;
      H3[(size_t)(jb + (kg<<2) + r) * 256 + c] = v;
      cs += v; cq += v*v;
    }
    cs += __shfl_xor(cs, 16); cs += __shfl_xor(cs, 32);
    cq += __shfl_xor(cq, 16); cq += __shfl_xor(cq, 32);
    if (kg == 0) { atomicAdd(&colsum[c], cs); atomicAdd(&colsq[c], cq); }
  }
}

// ---------------------------------------------------------------------------
// K2: fused BN1+leaky+adain2 -> xs = H4 @ gat_w.T, a_s, a_d.
// Blocks 0..1023: GEMM (waves split K, LDS combine).
// Blocks 1024..2047: counting-sort scatter (overlapped; needs only scan+ei).
// ---------------------------------------------------------------------------
__global__ __launch_bounds__(256) void k_gemm3(
    const float* __restrict__ H3, const float* __restrict__ colsum,
    const float* __restrict__ colsq, const float* __restrict__ bn1_g,
    const float* __restrict__ bn1_b, const float* __restrict__ gb,
    const u16* __restrict__ gatpk,
    const float* __restrict__ att_s, const float* __restrict__ att_d,
    float* __restrict__ xs, float* __restrict__ a_s, float* __restrict__ a_d,
    const int* __restrict__ src, const int* __restrict__ dstE,
    int* __restrict__ cur, int* __restrict__ ssrc)
{
  if (blockIdx.x >= 1024) {           // fused scatter: 1024 blocks
    int t = ((blockIdx.x - 1024) << 8) + threadIdx.x;
    #pragma unroll
    for (int i = 0; i < 4; ++i) {
      int e = t + i * 262144;
      int s = src[e], d = dstE[e];
      int p = atomicAdd(&cur[d], 1);
      ssrc[p] = s;
    }
    return;
  }
  const int lane = threadIdx.x & 63, wv = threadIdx.x >> 6;
  const int jb = blockIdx.x << 4;
  const int c0 = lane & 15, kg = lane >> 4;
  const int row = jb + c0;
  const int col0 = (wv << 6) + (kg << 3);         // + kk*32
  const float* g2  = gb + 128;
  const float* be2 = gb + 384;

  f32x4 w4[4];
  float ps = 0.f, pq = 0.f;
  #pragma unroll
  for (int kk = 0; kk < 2; ++kk) {
    #pragma unroll
    for (int h = 0; h < 2; ++h) {
      int c = col0 + kk*32 + h*4;
      f32x4 v  = *(const f32x4*)(H3 + (size_t)row*256 + c);
      f32x4 cm = *(const f32x4*)(colsum + c);
      f32x4 cq = *(const f32x4*)(colsq + c);
      f32x4 gg = *(const f32x4*)(bn1_g + c);
      f32x4 bb = *(const f32x4*)(bn1_b + c);
      f32x4 t;
      #pragma unroll
      for (int i = 0; i < 4; ++i) {
        float m  = cm[i] * (1.f/16384.f);
        float va = cq[i] * (1.f/16384.f) - m*m;
        float u  = (v[i]-m) * rsqrtf(va + 1e-5f) * gg[i] + bb[i];
        u = lrelu(u);
        t[i] = u; ps += u; pq += u*u;
      }
      w4[kk*2+h] = t;
    }
  }
  ps += __shfl_xor(ps, 16); ps += __shfl_xor(ps, 32);
  pq += __shfl_xor(pq, 16); pq += __shfl_xor(pq, 32);
  __shared__ float sps[64], sqs[64];
  if (kg == 0) { sps[(wv<<4) + c0] = ps; sqs[(wv<<4) + c0] = pq; }
  __syncthreads();
  float rs = sps[c0] + sps[16+c0] + sps[32+c0] + sps[48+c0];
  float rq = sqs[c0] + sqs[16+c0] + sqs[32+c0] + sqs[48+c0];
  float mean = rs * (1.f/256.f);
  float var  = rq * (1.f/256.f) - mean*mean;
  float sd   = sqrtf(fmaxf(var, 0.f) * (256.f/255.f));
  float id   = 1.f / (sd + 1e-8f);
  bf16x8 afr[2];
  #pragma unroll
  for (int kk = 0; kk < 2; ++kk) {
    f32x4 o[2];
    #pragma unroll
    for (int h = 0; h < 2; ++h) {
      int c = col0 + kk*32 + h*4;
      f32x4 ga = *(const f32x4*)(g2 + c);
      f32x4 bd = *(const f32x4*)(be2 + c);
      #pragma unroll
      for (int i = 0; i < 4; ++i) o[h][i] = ga[i]*(w4[kk*2+h][i]-mean)*id + bd[i];
    }
    afr[kk] = cvt8(o[0], o[1]);
  }
  const bf16x8* bpv = ((const bf16x8*)gatpk) + lane;
  f32x4 z = {0.f,0.f,0.f,0.f};
  f32x4 acc[4] = {z,z,z,z};
  #pragma unroll
  for (int kk = 0; kk < 2; ++kk) {
    int kt = (wv << 1) | kk;
    #pragma unroll
    for (int nt = 0; nt < 4; ++nt)
      acc[nt] = __builtin_amdgcn_mfma_f32_16x16x32_bf16(afr[kk], bpv[((kt<<2)+nt)*64], acc[nt], 0,0,0);
  }
  __shared__ float lred[3 * 16 * 64];
  if (wv) {
    float* rp = lred + ((wv - 1) << 10) + lane;
    #pragma unroll
    for (int nt = 0; nt < 4; ++nt)
      #pragma unroll
      for (int r = 0; r < 4; ++r) rp[((nt<<2)+r)<<6] = acc[nt][r];
  }
  __syncthreads();
  if (wv) return;
  float as0 = att_s[c0], as1 = att_s[c0+16], as2 = att_s[c0+32], as3 = att_s[c0+48];
  float ad0 = att_d[c0], ad1 = att_d[c0+16], ad2 = att_d[c0+32], ad3 = att_d[c0+48];
  const float* rp = lred + lane;
  #pragma unroll
  for (int r = 0; r < 4; ++r) {
    int j = jb + (kg << 2) + r;
    float v[4];
    #pragma unroll
    for (int nt = 0; nt < 4; ++nt) {
      int idx = ((nt<<2)+r)<<6;
      v[nt] = acc[nt][r] + rp[idx] + rp[idx+1024] + rp[idx+2048];
    }
    float* op = xs + (size_t)j * 64 + c0;
    op[0] = v[0]; op[16] = v[1]; op[32] = v[2]; op[48] = v[3];
    float ss = red16(v[0]*as0 + v[1]*as1 + v[2]*as2 + v[3]*as3);
    float dd = red16(v[0]*ad0 + v[1]*ad1 + v[2]*ad2 + v[3]*ad3);
    if (c0 == 0) { a_s[j] = ss; a_d[j] = dd; }
  }
}

// K3: per-dst segment softmax (no max-shift; e is bounded) + weighted gather
// + leaky + adain3 -> d_out. 16 lanes/edge, 4 edges in parallel.
__global__ __launch_bounds__(256) void k_gat(
    const int* __restrict__ cnt, const int* __restrict__ off,
    const int* __restrict__ ssrc, const float* __restrict__ a_s,
    const float* __restrict__ a_d,
    const float* __restrict__ xs, const float* __restrict__ gat_b,
    const float* __restrict__ g3, const float* __restrict__ be3,
    float* __restrict__ out)
{
  const int lane = threadIdx.x & 63, wv = threadIdx.x >> 6;
  const int j = (blockIdx.x << 2) | wv;
  const int n = cnt[j], beg = off[j];
  const int c4 = (lane & 15) << 2;
  const int eq = lane >> 4;
  const float adj = a_d[j];
  f32x4 acc = {0.f,0.f,0.f,0.f};
  float den = 0.f;
  if (n > 0) {
    for (int ch = 0; ch < n; ch += 64) {
      int k = ch + lane;
      bool ok = k < n;
      int   s = ok ? ssrc[beg + k] : 0;
      float p = ok ? __expf(lrelu(a_s[s] + adj)) : 0.f;
      den += p;
      int m = n - ch; if (m > 64) m = 64;
      int iters = (m + 3) >> 2;
      for (int i = 0; i < iters; ++i) {
        int idx = (i << 2) | eq;
        float pi = __shfl(p, idx);
        int   si = __shfl(s, idx);
        f32x4 v = *(const f32x4*)(xs + (size_t)si * 64 + c4);
        acc += pi * v;
      }
    }
    den = red64(den);
    #pragma unroll
    for (int i = 0; i < 4; ++i) { acc[i] += __shfl_xor(acc[i], 16); acc[i] += __shfl_xor(acc[i], 32); }
    float rd = 1.f / den;
    acc *= rd;
  }
  f32x4 gbv = *(const f32x4*)(gat_b + c4);
  float v0 = lrelu(acc[0] + gbv[0]);
  float v1 = lrelu(acc[1] + gbv[1]);
  float v2 = lrelu(acc[2] + gbv[2]);
  float v3 = lrelu(acc[3] + gbv[3]);
  float s = red16(v0+v1+v2+v3);
  float q = red16(v0*v0+v1*v1+v2*v2+v3*v3);
  float mean = s * (1.f/64.f);
  float var  = q * (1.f/64.f) - mean*mean;
  float sd   = sqrtf(fmaxf(var, 0.f) * (64.f/63.f));
  float id   = 1.f / (sd + 1e-8f);
  if (eq == 0) {
    f32x4 gv = *(const f32x4*)(g3 + c4);
    f32x4 bv = *(const f32x4*)(be3 + c4);
    f32x4 o;
    o[0] = gv[0]*(v0-mean)*id + bv[0];
    o[1] = gv[1]*(v1-mean)*id + bv[1];
    o[2] = gv[2]*(v2-mean)*id + bv[2];
    o[3] = gv[3]*(v3-mean)*id + bv[3];
    *(f32x4*)(out + (size_t)j * 64 + c4) = o;
  }
}

// ---------------------------------------------------------------------------
extern "C" void kernel_launch(void* const* d_in, const int* in_sizes, int n_in,
                              void* d_out, int out_size, void* d_ws, size_t ws_size,
                              hipStream_t stream) {
  (void)in_sizes; (void)n_in; (void)out_size; (void)ws_size;
  const float* x      = (const float*)d_in[0];
  const float* style  = (const float*)d_in[1];
  const int*   ei     = (const int*)d_in[2];
  const float* trs_w  = (const float*)d_in[3];
  const float* trs_b  = (const float*)d_in[4];
  const float* bn2_g  = (const float*)d_in[5];
  const float* bn2_b  = (const float*)d_in[6];
  const float* fc1_w  = (const float*)d_in[7];
  const float* fc1_b  = (const float*)d_in[8];
  const float* bn1_g  = (const float*)d_in[9];
  const float* bn1_b  = (const float*)d_in[10];
  const float* gat_w  = (const float*)d_in[11];
  const float* att_s  = (const float*)d_in[12];
  const float* att_d  = (const float*)d_in[13];
  const float* gat_b  = (const float*)d_in[14];
  const float* a1w1   = (const float*)d_in[15];
  const float* a1b1   = (const float*)d_in[16];
  const float* a1w2   = (const float*)d_in[17];
  const float* a1b2   = (const float*)d_in[18];
  const float* a2w1   = (const float*)d_in[19];
  const float* a2b1   = (const float*)d_in[20];
  const float* a2w2   = (const float*)d_in[21];
  const float* a2b2   = (const float*)d_in[22];
  const float* a3w1   = (const float*)d_in[23];
  const float* a3b1   = (const float*)d_in[24];
  const float* a3w2   = (const float*)d_in[25];
  const float* a3b2   = (const float*)d_in[26];

  char* ws = (char*)d_ws;
  u16*   xpk    = (u16*)(ws);                    // 2,097,152 B
  u16*   fc1pk  = (u16*)(ws + 2097152);          //    32,768 B
  u16*   gatpk  = (u16*)(ws + 2129920);          //    32,768 B
  float* gb     = (float*)(ws + 2162688);        //     3,072 B
  float* H3     = (float*)(ws + 6361088);        // 16,777,216 B
  float* xs     = (float*)(ws + 39915520);       // 4,194,304 B
  float* as_    = (float*)(ws + 44109824);       //    65,536 B
  float* ad_    = (float*)(ws + 44175360);       //    65,536 B
  float* colsum = (float*)(ws + 44240896);       //     1,024 B
  float* colsq  = (float*)(ws + 44241920);       //     1,024 B
  int*   cnt    = (int*)(ws + 44242944);         //    65,536 B
  int*   off    = (int*)(ws + 44308480);         //    65,536 B
  int*   cur    = (int*)(ws + 44374016);         //    65,536 B
  int*   ssrc   = (int*)(ws + 44439552);         // 4,194,304 B

  hipMemsetAsync(colsum, 0, 2048, stream);       // colsum + colsq
  hipMemsetAsync(cnt, 0, 65536, stream);

  k_prep<<<1555, 256, 0, stream>>>(x, style, fc1_w, gat_w,
      a1w1, a1b1, a1w2, a1b2, a2w1, a2b1, a2w2, a2b2, a3w1, a3b1, a3w2, a3b2,
      xpk, fc1pk, gatpk, gb, ei + NEDGE, cnt);
  k_gemm12<<<1025, 256, 0, stream>>>(trs_w, xpk, trs_b, bn2_g, bn2_b,
      gb, gb + 64, fc1pk, fc1_b, H3, colsum, colsq, cnt, off, cur);
  k_gemm3<<<2048, 256, 0, stream>>>(H3, colsum, colsq, bn1_g, bn1_b, gb,
      gatpk, att_s, att_d, xs, as_, ad_, ei, ei + NEDGE, cur, ssrc);
  k_gat<<<4096, 256, 0, stream>>>(cnt, off, ssrc, as_, ad_, xs, gat_b,
      gb + 640, gb + 704, (float*)d_out);
}

// Round 12
// 375.924 us; speedup vs baseline: 1.0205x; 1.0205x over previous
//
#include <hip/hip_runtime.h>
#include <hip/hip_bf16.h>

#define N_NODES 16384
#define NEDGE   1048576

typedef __attribute__((ext_vector_type(4))) float f32x4;
typedef __attribute__((ext_vector_type(4))) unsigned u32x4;
typedef __attribute__((ext_vector_type(8))) short bf16x8;
typedef __attribute__((ext_vector_type(8))) unsigned short u16x8;
typedef unsigned short u16;

__device__ __forceinline__ short f2bf(float f) {
  union { float f; unsigned u; } v; v.f = f;
  unsigned r = v.u + 0x7FFFu + ((v.u >> 16) & 1u);  // RNE
  return (short)(r >> 16);
}
__device__ __forceinline__ float bf2f(unsigned short h) {
  union { unsigned u; float f; } v; v.u = ((unsigned)h) << 16;
  return v.f;
}
__device__ __forceinline__ unsigned pk2(float lo, float hi) {
  __hip_bfloat162 h = __float22bfloat162_rn(make_float2(lo, hi));
  return *reinterpret_cast<unsigned*>(&h);
}
__device__ __forceinline__ bf16x8 cvt8(f32x4 a, f32x4 b) {
  u32x4 u;
  u[0] = pk2(a[0], a[1]); u[1] = pk2(a[2], a[3]);
  u[2] = pk2(b[0], b[1]); u[3] = pk2(b[2], b[3]);
  return __builtin_bit_cast(bf16x8, u);
}
__device__ __forceinline__ float red16(float v) {
  v += __shfl_xor(v, 1); v += __shfl_xor(v, 2);
  v += __shfl_xor(v, 4); v += __shfl_xor(v, 8);
  return v;
}
__device__ __forceinline__ float red64(float v) {
  v += __shfl_xor(v, 1); v += __shfl_xor(v, 2); v += __shfl_xor(v, 4);
  v += __shfl_xor(v, 8); v += __shfl_xor(v, 16); v += __shfl_xor(v, 32);
  return v;
}
__device__ __forceinline__ float lrelu(float x){ return x >= 0.f ? x : 0.2f*x; }

// ---------------------------------------------------------------------------
// Prep: pack x / fc1_w / gat_w into MFMA B-fragment order (bf16), compute the
// six style gamma/beta vectors. Blocks >= 531 run the edge histogram
// (cnt pre-zeroed by hipMemsetAsync before this kernel).
// gb layout: g1[64] be1[64] g2[256] be2[256] g3[64] be3[64]
// ---------------------------------------------------------------------------
__global__ __launch_bounds__(256) void k_prep(
    const float* __restrict__ x, const float* __restrict__ style,
    const float* __restrict__ fc1_w, const float* __restrict__ gat_w,
    const float* __restrict__ a1w1, const float* __restrict__ a1b1,
    const float* __restrict__ a1w2, const float* __restrict__ a1b2,
    const float* __restrict__ a2w1, const float* __restrict__ a2b1,
    const float* __restrict__ a2w2, const float* __restrict__ a2b2,
    const float* __restrict__ a3w1, const float* __restrict__ a3b1,
    const float* __restrict__ a3w2, const float* __restrict__ a3b2,
    u16* __restrict__ xpk, u16* __restrict__ fc1pk, u16* __restrict__ gatpk,
    float* __restrict__ gb, const int* __restrict__ dst, int* __restrict__ cnt)
{
  if (blockIdx.x >= 531) {            // fused histogram: 1024 blocks
    int t = ((blockIdx.x - 531) << 8) + threadIdx.x;
    #pragma unroll
    for (int i = 0; i < 4; ++i) atomicAdd(&cnt[dst[t + i*262144]], 1);
    return;
  }
  int tid = blockIdx.x * 256 + threadIdx.x;
  if (tid < 131072) {                 // xpk: 512 ktiles x 4 ntiles x 64 lanes
    int lane = tid & 63;
    int kt = tid >> 8, nt = (tid >> 6) & 3;
    int k0 = kt*32 + (lane>>4)*8, c = nt*16 + (lane&15);
    bf16x8 o;
    #pragma unroll
    for (int j = 0; j < 8; ++j) o[j] = f2bf(x[(size_t)(k0+j)*64 + c]);
    ((bf16x8*)xpk)[tid] = o;
  } else if (tid < 133120) {          // fc1pk: 2 ktiles x 16 ntiles x 64 lanes
    int t2 = tid - 131072;
    int lane = t2 & 63, kt = t2 >> 10, nt = (t2 >> 6) & 15;
    int k0 = kt*32 + (lane>>4)*8, c = nt*16 + (lane&15);
    bf16x8 o;
    #pragma unroll
    for (int j = 0; j < 8; ++j) o[j] = f2bf(fc1_w[(size_t)c*64 + k0 + j]);
    ((bf16x8*)fc1pk)[t2] = o;
  } else if (tid < 135168) {          // gatpk: 8 ktiles x 4 ntiles x 64 lanes
    int t3 = tid - 133120;
    int lane = t3 & 63, kt = t3 >> 8, nt = (t3 >> 6) & 3;
    int k0 = kt*32 + (lane>>4)*8, c = nt*16 + (lane&15);
    bf16x8 o;
    #pragma unroll
    for (int j = 0; j < 8; ++j) o[j] = f2bf(gat_w[(size_t)c*256 + k0 + j]);
    ((bf16x8*)gatpk)[t3] = o;
  } else if (tid < 135936) {          // gamma/beta dots
    int t4 = tid - 135168;
    const float* wp; const float* bp; float* op; int d;
    if (t4 < 64)       { wp=a1w1; bp=a1b1; op=gb;       d=t4; }
    else if (t4 < 128) { wp=a1w2; bp=a1b2; op=gb+64;    d=t4-64; }
    else if (t4 < 384) { wp=a2w1; bp=a2b1; op=gb+128;   d=t4-128; }
    else if (t4 < 640) { wp=a2w2; bp=a2b2; op=gb+384;   d=t4-384; }
    else if (t4 < 704) { wp=a3w1; bp=a3b1; op=gb+640;   d=t4-640; }
    else               { wp=a3w2; bp=a3b2; op=gb+704;   d=t4-704; }
    float s = bp[d];
    for (int k = 0; k < 64; ++k) s += wp[(size_t)d*64 + k] * style[k];
    op[d] = s;
  }
}

// ---------------------------------------------------------------------------
// K1: fused gemm1 + BN2 + leaky + adain1 + gemm2 + colstats.
// LDS-staged W-stream, 3-deep register pipeline (P/Q sets, unroll-2).
// Contiguous 1KB/instruction loads, XOR-swizzled 16B units.
// Wave w owns n-tile w. Block 1024 = counting-sort scan.
// ---------------------------------------------------------------------------
__global__ __launch_bounds__(256, 4) void k_gemm12(
    const float* __restrict__ W, const u16* __restrict__ xpk,
    const float* __restrict__ trs_b, const float* __restrict__ bn2_g,
    const float* __restrict__ bn2_b, const float* __restrict__ g1,
    const float* __restrict__ be1,
    const u16* __restrict__ fc1pk, const float* __restrict__ fc1_b,
    float* __restrict__ H3, float* __restrict__ colsum, float* __restrict__ colsq,
    const int* __restrict__ cnt, int* __restrict__ off, int* __restrict__ cur)
{
  if (blockIdx.x == 1024) {           // fused scan (counting-sort offsets)
    __shared__ int ps[256];
    int t = threadIdx.x;
    int base = t * 64;
    int s = 0;
    for (int i = 0; i < 64; ++i) s += cnt[base + i];
    ps[t] = s;
    __syncthreads();
    for (int d = 1; d < 256; d <<= 1) {
      int v = (t >= d) ? ps[t - d] : 0;
      __syncthreads();
      ps[t] += v;
      __syncthreads();
    }
    int run = ps[t] - s;
    for (int i = 0; i < 64; ++i) {
      off[base + i] = run; cur[base + i] = run;
      run += cnt[base + i];
    }
    return;
  }
  const int tid  = threadIdx.x;
  const int lane = tid & 63;
  const int wv   = tid >> 6;
  const int jb   = blockIdx.x << 4;
  const int c0   = lane & 15, kg = lane >> 4;
  const int sw   = c0 & 7;

  __shared__ __align__(16) float lbuf[2][4096];   // [buf][row*256 + unit16B*4]
  __shared__ float h2t[16 * 68];

  // staging: thread covers rows wv+4i (i=0..3), 16B-unit `lane` of each 1KB chunk
  const float* gsrc[4];
  int ldst[4];
  #pragma unroll
  for (int i = 0; i < 4; ++i) {
    int r = wv + (i << 2);
    gsrc[i] = W + (size_t)(jb + r) * 16384 + (size_t)((lane ^ (r & 7)) << 2);
    ldst[i] = ((r << 6) + lane) << 2;
  }

  const int it0 = blockIdx.x & 63;               // K start-phase rotation
  f32x4 z = {0.f,0.f,0.f,0.f};
  f32x4 acc = z;
  f32x4 P[4], Q[4];

  {   // prologue: stage chunk 0 directly; P <- chunk 1, Q <- chunk 2
    int kk0 = it0 << 8;
    #pragma unroll
    for (int i = 0; i < 4; ++i) {
      f32x4 v = __builtin_nontemporal_load((const f32x4*)(gsrc[i] + kk0));
      *(f32x4*)&lbuf[0][ldst[i]] = v;
    }
    int kk1 = ((it0 + 1) & 63) << 8;
    #pragma unroll
    for (int i = 0; i < 4; ++i)
      P[i] = __builtin_nontemporal_load((const f32x4*)(gsrc[i] + kk1));
    int kk2 = ((it0 + 2) & 63) << 8;
    #pragma unroll
    for (int i = 0; i < 4; ++i)
      Q[i] = __builtin_nontemporal_load((const f32x4*)(gsrc[i] + kk2));
  }
  __syncthreads();

  const bf16x8* xb = ((const bf16x8*)xpk) + (wv << 6) + lane;

#define G1_BODY(ITX, R) do {                                                 \
    const int it_ = (ITX);                                                   \
    {                                                                        \
      float* lo_ = lbuf[(it_ + 1) & 1];                                      \
      _Pragma("unroll")                                                      \
      for (int i = 0; i < 4; ++i) *(f32x4*)&lo_[ldst[i]] = R[i];             \
    }                                                                        \
    if (it_ <= 60) {                                                         \
      int kk_ = ((it_ + 3 + it0) & 63) << 8;                                 \
      _Pragma("unroll")                                                      \
      for (int i = 0; i < 4; ++i)                                            \
        R[i] = __builtin_nontemporal_load((const f32x4*)(gsrc[i] + kk_));    \
    }                                                                        \
    {                                                                        \
      int ktg0_ = ((it_ + it0) & 63) << 3;                                   \
      const float* lb_ = lbuf[it_ & 1] + (c0 << 8);                          \
      const bf16x8* bp_ = xb + (size_t)ktg0_ * 256;                          \
      _Pragma("unroll")                                                      \
      for (int kt = 0; kt < 8; ++kt) {                                       \
        int u0_ = (kt << 3) + (kg << 1);                                     \
        f32x4 a0 = *(const f32x4*)(lb_ + ((u0_ ^ sw) << 2));                 \
        f32x4 a1 = *(const f32x4*)(lb_ + (((u0_ + 1) ^ sw) << 2));           \
        bf16x8 b = bp_[(size_t)kt << 8];                                     \
        acc = __builtin_amdgcn_mfma_f32_16x16x32_bf16(cvt8(a0, a1), b, acc, 0,0,0); \
      }                                                                      \
    }                                                                        \
    __syncthreads();                                                         \
  } while (0)

  for (int i2 = 0; i2 < 31; ++i2) {
    G1_BODY(2 * i2,     P);
    G1_BODY(2 * i2 + 1, Q);
  }
  G1_BODY(62, P);
  {   // epilogue: compute chunk 63 (already staged), no write/issue
    int ktg0 = ((63 + it0) & 63) << 3;
    const float* lb = lbuf[1] + (c0 << 8);
    const bf16x8* bp = xb + (size_t)ktg0 * 256;
    #pragma unroll
    for (int kt = 0; kt < 8; ++kt) {
      int u0 = (kt << 3) + (kg << 1);
      f32x4 a0 = *(const f32x4*)(lb + ((u0 ^ sw) << 2));
      f32x4 a1 = *(const f32x4*)(lb + (((u0 + 1) ^ sw) << 2));
      bf16x8 b = bp[(size_t)kt << 8];
      acc = __builtin_amdgcn_mfma_f32_16x16x32_bf16(cvt8(a0, a1), b, acc, 0,0,0);
    }
  }
#undef G1_BODY
  __syncthreads();

  // dump acc tile: rows kg*4+i (block-local), cols wv*16+c0
  #pragma unroll
  for (int i = 0; i < 4; ++i)
    h2t[((kg << 2) + i) * 68 + (wv << 4) + c0] = acc[i];
  __syncthreads();

  // BN2 + leaky + adain1, row-parallel: wave wv handles rows 4wv..4wv+3
  #pragma unroll
  for (int i = 0; i < 4; ++i) {
    int jr = (wv << 2) + i;
    int j  = jb + jr;
    float v = h2t[jr * 68 + lane] + trs_b[j];
    float s = red64(v), q = red64(v * v);
    float mean = s * 0.015625f;
    float var  = q * 0.015625f - mean * mean;
    float inv  = rsqrtf(var + 1e-5f) * bn2_g[j];
    v = lrelu((v - mean) * inv + bn2_b[j]);
    s = red64(v); q = red64(v * v);
    mean = s * 0.015625f;
    var  = q * 0.015625f - mean * mean;
    float sd = sqrtf(fmaxf(var, 0.f) * (64.f / 63.f));
    float id = 1.f / (sd + 1e-8f);
    h2t[jr * 68 + lane] = g1[lane] * (v - mean) * id + be1[lane];
  }
  __syncthreads();

  // gemm2 on the LDS tile: H3 tile = h2t @ fc1_w.T + colstats
  const float* ha = h2t + c0 * 68 + (kg << 3);
  bf16x8 a0 = cvt8(*(const f32x4*)ha,        *(const f32x4*)(ha+4));
  bf16x8 a1 = cvt8(*(const f32x4*)(ha+32),   *(const f32x4*)(ha+36));
  const bf16x8* fpv = ((const bf16x8*)fc1pk) + lane;
  f32x4 acc2[4] = {z,z,z,z};
  #pragma unroll
  for (int q = 0; q < 4; ++q) {
    int nt = (wv << 2) | q;
    acc2[q] = __builtin_amdgcn_mfma_f32_16x16x32_bf16(a0, fpv[nt*64],      acc2[q], 0,0,0);
    acc2[q] = __builtin_amdgcn_mfma_f32_16x16x32_bf16(a1, fpv[(16+nt)*64], acc2[q], 0,0,0);
  }
  #pragma unroll
  for (int q = 0; q < 4; ++q) {
    int c = (((wv << 2) | q) << 4) + c0;
    float bias = fc1_b[c];
    float cs = 0.f, cq = 0.f;
    #pragma unroll
    for (int r = 0; r < 4; ++r) {
      float v = acc2[q][r] + bias;
      H3[(size_t)(jb + (kg<<2) + r) * 256 + c] = v;
      cs += v; cq += v*v;
    }
    cs += __shfl_xor(cs, 16); cs += __shfl_xor(cs, 32);
    cq += __shfl_xor(cq, 16); cq += __shfl_xor(cq, 32);
    if (kg == 0) { atomicAdd(&colsum[c], cs); atomicAdd(&colsq[c], cq); }
  }
}

// ---------------------------------------------------------------------------
// K2: fused BN1+leaky+adain2 -> xs(bf16) = H4 @ gat_w.T, a_s, a_d.
// Blocks 0..1023: GEMM (waves split K, LDS combine).
// Blocks 1024..2047: counting-sort scatter (overlapped; needs only scan+ei).
// ---------------------------------------------------------------------------
__global__ __launch_bounds__(256) void k_gemm3(
    const float* __restrict__ H3, const float* __restrict__ colsum,
    const float* __restrict__ colsq, const float* __restrict__ bn1_g,
    const float* __restrict__ bn1_b, const float* __restrict__ gb,
    const u16* __restrict__ gatpk,
    const float* __restrict__ att_s, const float* __restrict__ att_d,
    u16* __restrict__ xs, float* __restrict__ a_s, float* __restrict__ a_d,
    const int* __restrict__ src, const int* __restrict__ dstE,
    int* __restrict__ cur, int* __restrict__ ssrc)
{
  if (blockIdx.x >= 1024) {           // fused scatter: 1024 blocks
    int t = ((blockIdx.x - 1024) << 8) + threadIdx.x;
    #pragma unroll
    for (int i = 0; i < 4; ++i) {
      int e = t + i * 262144;
      int s = src[e], d = dstE[e];
      int p = atomicAdd(&cur[d], 1);
      ssrc[p] = s;
    }
    return;
  }
  const int lane = threadIdx.x & 63, wv = threadIdx.x >> 6;
  const int jb = blockIdx.x << 4;
  const int c0 = lane & 15, kg = lane >> 4;
  const int row = jb + c0;
  const int col0 = (wv << 6) + (kg << 3);         // + kk*32
  const float* g2  = gb + 128;
  const float* be2 = gb + 384;

  f32x4 w4[4];
  float ps = 0.f, pq = 0.f;
  #pragma unroll
  for (int kk = 0; kk < 2; ++kk) {
    #pragma unroll
    for (int h = 0; h < 2; ++h) {
      int c = col0 + kk*32 + h*4;
      f32x4 v  = *(const f32x4*)(H3 + (size_t)row*256 + c);
      f32x4 cm = *(const f32x4*)(colsum + c);
      f32x4 cq = *(const f32x4*)(colsq + c);
      f32x4 gg = *(const f32x4*)(bn1_g + c);
      f32x4 bb = *(const f32x4*)(bn1_b + c);
      f32x4 t;
      #pragma unroll
      for (int i = 0; i < 4; ++i) {
        float m  = cm[i] * (1.f/16384.f);
        float va = cq[i] * (1.f/16384.f) - m*m;
        float u  = (v[i]-m) * rsqrtf(va + 1e-5f) * gg[i] + bb[i];
        u = lrelu(u);
        t[i] = u; ps += u; pq += u*u;
      }
      w4[kk*2+h] = t;
    }
  }
  ps += __shfl_xor(ps, 16); ps += __shfl_xor(ps, 32);
  pq += __shfl_xor(pq, 16); pq += __shfl_xor(pq, 32);
  __shared__ float sps[64], sqs[64];
  if (kg == 0) { sps[(wv<<4) + c0] = ps; sqs[(wv<<4) + c0] = pq; }
  __syncthreads();
  float rs = sps[c0] + sps[16+c0] + sps[32+c0] + sps[48+c0];
  float rq = sqs[c0] + sqs[16+c0] + sqs[32+c0] + sqs[48+c0];
  float mean = rs * (1.f/256.f);
  float var  = rq * (1.f/256.f) - mean*mean;
  float sd   = sqrtf(fmaxf(var, 0.f) * (256.f/255.f));
  float id   = 1.f / (sd + 1e-8f);
  bf16x8 afr[2];
  #pragma unroll
  for (int kk = 0; kk < 2; ++kk) {
    f32x4 o[2];
    #pragma unroll
    for (int h = 0; h < 2; ++h) {
      int c = col0 + kk*32 + h*4;
      f32x4 ga = *(const f32x4*)(g2 + c);
      f32x4 bd = *(const f32x4*)(be2 + c);
      #pragma unroll
      for (int i = 0; i < 4; ++i) o[h][i] = ga[i]*(w4[kk*2+h][i]-mean)*id + bd[i];
    }
    afr[kk] = cvt8(o[0], o[1]);
  }
  const bf16x8* bpv = ((const bf16x8*)gatpk) + lane;
  f32x4 z = {0.f,0.f,0.f,0.f};
  f32x4 acc[4] = {z,z,z,z};
  #pragma unroll
  for (int kk = 0; kk < 2; ++kk) {
    int kt = (wv << 1) | kk;
    #pragma unroll
    for (int nt = 0; nt < 4; ++nt)
      acc[nt] = __builtin_amdgcn_mfma_f32_16x16x32_bf16(afr[kk], bpv[((kt<<2)+nt)*64], acc[nt], 0,0,0);
  }
  __shared__ float lred[3 * 16 * 64];
  if (wv) {
    float* rp = lred + ((wv - 1) << 10) + lane;
    #pragma unroll
    for (int nt = 0; nt < 4; ++nt)
      #pragma unroll
      for (int r = 0; r < 4; ++r) rp[((nt<<2)+r)<<6] = acc[nt][r];
  }
  __syncthreads();
  if (wv) return;
  float as0 = att_s[c0], as1 = att_s[c0+16], as2 = att_s[c0+32], as3 = att_s[c0+48];
  float ad0 = att_d[c0], ad1 = att_d[c0+16], ad2 = att_d[c0+32], ad3 = att_d[c0+48];
  const float* rp = lred + lane;
  #pragma unroll
  for (int r = 0; r < 4; ++r) {
    int j = jb + (kg << 2) + r;
    float v[4];
    #pragma unroll
    for (int nt = 0; nt < 4; ++nt) {
      int idx = ((nt<<2)+r)<<6;
      v[nt] = acc[nt][r] + rp[idx] + rp[idx+1024] + rp[idx+2048];
    }
    u16* op = xs + (size_t)j * 64 + c0;
    op[0]  = (u16)f2bf(v[0]);
    op[16] = (u16)f2bf(v[1]);
    op[32] = (u16)f2bf(v[2]);
    op[48] = (u16)f2bf(v[3]);
    float ss = red16(v[0]*as0 + v[1]*as1 + v[2]*as2 + v[3]*as3);
    float dd = red16(v[0]*ad0 + v[1]*ad1 + v[2]*ad2 + v[3]*ad3);
    if (c0 == 0) { a_s[j] = ss; a_d[j] = dd; }
  }
}

// K3: per-dst segment softmax + weighted gather (bf16 xs, 8 edges x 8 lanes
// x 16B per step) + leaky + adain3 -> d_out.
__global__ __launch_bounds__(256) void k_gat(
    const int* __restrict__ cnt, const int* __restrict__ off,
    const int* __restrict__ ssrc, const float* __restrict__ a_s,
    const float* __restrict__ a_d,
    const u16* __restrict__ xs, const float* __restrict__ gat_b,
    const float* __restrict__ g3, const float* __restrict__ be3,
    float* __restrict__ out)
{
  const int lane = threadIdx.x & 63, wv = threadIdx.x >> 6;
  const int j = (blockIdx.x << 2) | wv;
  const int n = cnt[j], beg = off[j];
  const int c8 = (lane & 7) << 3;     // feature base (8 features/lane)
  const int eq = lane >> 3;           // edge slot 0..7
  const float adj = a_d[j];
  float acc[8] = {0.f,0.f,0.f,0.f,0.f,0.f,0.f,0.f};
  float den = 0.f;
  if (n > 0) {
    for (int ch = 0; ch < n; ch += 64) {
      int k = ch + lane;
      bool ok = k < n;
      int   s = ok ? ssrc[beg + k] : 0;
      float p = ok ? __expf(lrelu(a_s[s] + adj)) : 0.f;
      den += p;
      int m = n - ch; if (m > 64) m = 64;
      int iters = (m + 7) >> 3;
      for (int i = 0; i < iters; ++i) {
        int idx = (i << 3) | eq;
        float pi = __shfl(p, idx);
        int   si = __shfl(s, idx);
        u16x8 hv = *(const u16x8*)(xs + (size_t)si * 64 + c8);
        #pragma unroll
        for (int t = 0; t < 8; ++t) acc[t] += pi * bf2f(hv[t]);
      }
    }
    den = red64(den);
    #pragma unroll
    for (int t = 0; t < 8; ++t) {
      acc[t] += __shfl_xor(acc[t], 8);
      acc[t] += __shfl_xor(acc[t], 16);
      acc[t] += __shfl_xor(acc[t], 32);
    }
    float rd = 1.f / den;
    #pragma unroll
    for (int t = 0; t < 8; ++t) acc[t] *= rd;
  }
  // bias + leaky; per-lane partial stats over its 8 features
  float vv[8];
  float s8 = 0.f, q8 = 0.f;
  #pragma unroll
  for (int t = 0; t < 8; ++t) {
    float v = lrelu(acc[t] + gat_b[c8 + t]);
    vv[t] = v; s8 += v; q8 += v * v;
  }
  // total over 64 features: butterfly across the 8 feature-groups
  s8 += __shfl_xor(s8, 1); s8 += __shfl_xor(s8, 2); s8 += __shfl_xor(s8, 4);
  q8 += __shfl_xor(q8, 1); q8 += __shfl_xor(q8, 2); q8 += __shfl_xor(q8, 4);
  float mean = s8 * (1.f/64.f);
  float var  = q8 * (1.f/64.f) - mean*mean;
  float sd   = sqrtf(fmaxf(var, 0.f) * (64.f/63.f));
  float id   = 1.f / (sd + 1e-8f);
  if (eq == 0) {
    f32x4 o0, o1;
    #pragma unroll
    for (int t = 0; t < 4; ++t) {
      o0[t] = g3[c8+t]   * (vv[t]  -mean)*id + be3[c8+t];
      o1[t] = g3[c8+4+t] * (vv[4+t]-mean)*id + be3[c8+4+t];
    }
    float* op = out + (size_t)j * 64 + c8;
    *(f32x4*)op       = o0;
    *(f32x4*)(op + 4) = o1;
  }
}

// ---------------------------------------------------------------------------
extern "C" void kernel_launch(void* const* d_in, const int* in_sizes, int n_in,
                              void* d_out, int out_size, void* d_ws, size_t ws_size,
                              hipStream_t stream) {
  (void)in_sizes; (void)n_in; (void)out_size; (void)ws_size;
  const float* x      = (const float*)d_in[0];
  const float* style  = (const float*)d_in[1];
  const int*   ei     = (const int*)d_in[2];
  const float* trs_w  = (const float*)d_in[3];
  const float* trs_b  = (const float*)d_in[4];
  const float* bn2_g  = (const float*)d_in[5];
  const float* bn2_b  = (const float*)d_in[6];
  const float* fc1_w  = (const float*)d_in[7];
  const float* fc1_b  = (const float*)d_in[8];
  const float* bn1_g  = (const float*)d_in[9];
  const float* bn1_b  = (const float*)d_in[10];
  const float* gat_w  = (const float*)d_in[11];
  const float* att_s  = (const float*)d_in[12];
  const float* att_d  = (const float*)d_in[13];
  const float* gat_b  = (const float*)d_in[14];
  const float* a1w1   = (const float*)d_in[15];
  const float* a1b1   = (const float*)d_in[16];
  const float* a1w2   = (const float*)d_in[17];
  const float* a1b2   = (const float*)d_in[18];
  const float* a2w1   = (const float*)d_in[19];
  const float* a2b1   = (const float*)d_in[20];
  const float* a2w2   = (const float*)d_in[21];
  const float* a2b2   = (const float*)d_in[22];
  const float* a3w1   = (const float*)d_in[23];
  const float* a3b1   = (const float*)d_in[24];
  const float* a3w2   = (const float*)d_in[25];
  const float* a3b2   = (const float*)d_in[26];

  char* ws = (char*)d_ws;
  u16*   xpk    = (u16*)(ws);                    // 2,097,152 B
  u16*   fc1pk  = (u16*)(ws + 2097152);          //    32,768 B
  u16*   gatpk  = (u16*)(ws + 2129920);          //    32,768 B
  float* gb     = (float*)(ws + 2162688);        //     3,072 B
  float* H3     = (float*)(ws + 6361088);        // 16,777,216 B
  u16*   xs     = (u16*)(ws + 39915520);         // 2,097,152 B (bf16)
  float* as_    = (float*)(ws + 44109824);       //    65,536 B
  float* ad_    = (float*)(ws + 44175360);       //    65,536 B
  float* colsum = (float*)(ws + 44240896);       //     1,024 B
  float* colsq  = (float*)(ws + 44241920);       //     1,024 B
  int*   cnt    = (int*)(ws + 44242944);         //    65,536 B
  int*   off    = (int*)(ws + 44308480);         //    65,536 B
  int*   cur    = (int*)(ws + 44374016);         //    65,536 B
  int*   ssrc   = (int*)(ws + 44439552);         // 4,194,304 B

  hipMemsetAsync(colsum, 0, 2048, stream);       // colsum + colsq
  hipMemsetAsync(cnt, 0, 65536, stream);

  k_prep<<<1555, 256, 0, stream>>>(x, style, fc1_w, gat_w,
      a1w1, a1b1, a1w2, a1b2, a2w1, a2b1, a2w2, a2b2, a3w1, a3b1, a3w2, a3b2,
      xpk, fc1pk, gatpk, gb, ei + NEDGE, cnt);
  k_gemm12<<<1025, 256, 0, stream>>>(trs_w, xpk, trs_b, bn2_g, bn2_b,
      gb, gb + 64, fc1pk, fc1_b, H3, colsum, colsq, cnt, off, cur);
  k_gemm3<<<2048, 256, 0, stream>>>(H3, colsum, colsq, bn1_g, bn1_b, gb,
      gatpk, att_s, att_d, xs, as_, ad_, ei, ei + NEDGE, cur, ssrc);
  k_gat<<<4096, 256, 0, stream>>>(cnt, off, ssrc, as_, ad_, xs, gat_b,
      gb + 640, gb + 704, (float*)d_out);
}

// Round 13
// 372.060 us; speedup vs baseline: 1.0311x; 1.0104x over previous
//
#include <hip/hip_runtime.h>
#include <hip/hip_bf16.h>

#define N_NODES 16384
#define NEDGE   1048576

typedef __attribute__((ext_vector_type(4))) float f32x4;
typedef __attribute__((ext_vector_type(4))) unsigned u32x4;
typedef __attribute__((ext_vector_type(8))) short bf16x8;
typedef __attribute__((ext_vector_type(8))) unsigned short u16x8;
typedef unsigned short u16;

__device__ __forceinline__ short f2bf(float f) {
  union { float f; unsigned u; } v; v.f = f;
  unsigned r = v.u + 0x7FFFu + ((v.u >> 16) & 1u);  // RNE
  return (short)(r >> 16);
}
__device__ __forceinline__ float bf2f(unsigned short h) {
  union { unsigned u; float f; } v; v.u = ((unsigned)h) << 16;
  return v.f;
}
__device__ __forceinline__ unsigned pk2(float lo, float hi) {
  __hip_bfloat162 h = __float22bfloat162_rn(make_float2(lo, hi));
  return *reinterpret_cast<unsigned*>(&h);
}
__device__ __forceinline__ bf16x8 cvt8(f32x4 a, f32x4 b) {
  u32x4 u;
  u[0] = pk2(a[0], a[1]); u[1] = pk2(a[2], a[3]);
  u[2] = pk2(b[0], b[1]); u[3] = pk2(b[2], b[3]);
  return __builtin_bit_cast(bf16x8, u);
}
__device__ __forceinline__ float red16(float v) {
  v += __shfl_xor(v, 1); v += __shfl_xor(v, 2);
  v += __shfl_xor(v, 4); v += __shfl_xor(v, 8);
  return v;
}
__device__ __forceinline__ float red64(float v) {
  v += __shfl_xor(v, 1); v += __shfl_xor(v, 2); v += __shfl_xor(v, 4);
  v += __shfl_xor(v, 8); v += __shfl_xor(v, 16); v += __shfl_xor(v, 32);
  return v;
}
__device__ __forceinline__ float lrelu(float x){ return x >= 0.f ? x : 0.2f*x; }

// ---------------------------------------------------------------------------
// Prep: pack x / fc1_w / gat_w into MFMA B-fragment order (bf16), compute the
// six style gamma/beta vectors. Blocks >= 531 run the edge histogram
// (cnt pre-zeroed by hipMemsetAsync before this kernel).
// gb layout: g1[64] be1[64] g2[256] be2[256] g3[64] be3[64]
// ---------------------------------------------------------------------------
__global__ __launch_bounds__(256) void k_prep(
    const float* __restrict__ x, const float* __restrict__ style,
    const float* __restrict__ fc1_w, const float* __restrict__ gat_w,
    const float* __restrict__ a1w1, const float* __restrict__ a1b1,
    const float* __restrict__ a1w2, const float* __restrict__ a1b2,
    const float* __restrict__ a2w1, const float* __restrict__ a2b1,
    const float* __restrict__ a2w2, const float* __restrict__ a2b2,
    const float* __restrict__ a3w1, const float* __restrict__ a3b1,
    const float* __restrict__ a3w2, const float* __restrict__ a3b2,
    u16* __restrict__ xpk, u16* __restrict__ fc1pk, u16* __restrict__ gatpk,
    float* __restrict__ gb, const int* __restrict__ dst, int* __restrict__ cnt)
{
  if (blockIdx.x >= 531) {            // fused histogram: 1024 blocks
    int t = ((blockIdx.x - 531) << 8) + threadIdx.x;
    #pragma unroll
    for (int i = 0; i < 4; ++i) atomicAdd(&cnt[dst[t + i*262144]], 1);
    return;
  }
  int tid = blockIdx.x * 256 + threadIdx.x;
  if (tid < 131072) {                 // xpk: 512 ktiles x 4 ntiles x 64 lanes
    int lane = tid & 63;
    int kt = tid >> 8, nt = (tid >> 6) & 3;
    int k0 = kt*32 + (lane>>4)*8, c = nt*16 + (lane&15);
    bf16x8 o;
    #pragma unroll
    for (int j = 0; j < 8; ++j) o[j] = f2bf(x[(size_t)(k0+j)*64 + c]);
    ((bf16x8*)xpk)[tid] = o;
  } else if (tid < 133120) {          // fc1pk: 2 ktiles x 16 ntiles x 64 lanes
    int t2 = tid - 131072;
    int lane = t2 & 63, kt = t2 >> 10, nt = (t2 >> 6) & 15;
    int k0 = kt*32 + (lane>>4)*8, c = nt*16 + (lane&15);
    bf16x8 o;
    #pragma unroll
    for (int j = 0; j < 8; ++j) o[j] = f2bf(fc1_w[(size_t)c*64 + k0 + j]);
    ((bf16x8*)fc1pk)[t2] = o;
  } else if (tid < 135168) {          // gatpk: 8 ktiles x 4 ntiles x 64 lanes
    int t3 = tid - 133120;
    int lane = t3 & 63, kt = t3 >> 8, nt = (t3 >> 6) & 3;
    int k0 = kt*32 + (lane>>4)*8, c = nt*16 + (lane&15);
    bf16x8 o;
    #pragma unroll
    for (int j = 0; j < 8; ++j) o[j] = f2bf(gat_w[(size_t)c*256 + k0 + j]);
    ((bf16x8*)gatpk)[t3] = o;
  } else if (tid < 135936) {          // gamma/beta dots
    int t4 = tid - 135168;
    const float* wp; const float* bp; float* op; int d;
    if (t4 < 64)       { wp=a1w1; bp=a1b1; op=gb;       d=t4; }
    else if (t4 < 128) { wp=a1w2; bp=a1b2; op=gb+64;    d=t4-64; }
    else if (t4 < 384) { wp=a2w1; bp=a2b1; op=gb+128;   d=t4-128; }
    else if (t4 < 640) { wp=a2w2; bp=a2b2; op=gb+384;   d=t4-384; }
    else if (t4 < 704) { wp=a3w1; bp=a3b1; op=gb+640;   d=t4-640; }
    else               { wp=a3w2; bp=a3b2; op=gb+704;   d=t4-704; }
    float s = bp[d];
    for (int k = 0; k < 64; ++k) s += wp[(size_t)d*64 + k] * style[k];
    op[d] = s;
  }
}

// ---------------------------------------------------------------------------
// K1: fused gemm1 + BN2 + leaky + adain1 + gemm2 + colstats.
// LDS-staged W-stream (3-deep reg pipeline, contiguous 1KB loads, XOR swizzle)
// with K-SPLIT waves: wave wv computes ktiles {2wv,2wv+1} of each chunk for
// all 4 n-tiles (4x fewer LDS reads, 4 independent MFMA chains). K-split
// combine + BN2/adain1 epilogue on wave 0 (lred/h2t alias dead lbuf halves).
// Block 1024 = counting-sort scan.
// ---------------------------------------------------------------------------
__global__ __launch_bounds__(256, 4) void k_gemm12(
    const float* __restrict__ W, const u16* __restrict__ xpk,
    const float* __restrict__ trs_b, const float* __restrict__ bn2_g,
    const float* __restrict__ bn2_b, const float* __restrict__ g1,
    const float* __restrict__ be1,
    const u16* __restrict__ fc1pk, const float* __restrict__ fc1_b,
    float* __restrict__ H3, float* __restrict__ colsum, float* __restrict__ colsq,
    const int* __restrict__ cnt, int* __restrict__ off, int* __restrict__ cur)
{
  if (blockIdx.x == 1024) {           // fused scan (counting-sort offsets)
    __shared__ int ps[256];
    int t = threadIdx.x;
    int base = t * 64;
    int s = 0;
    for (int i = 0; i < 64; ++i) s += cnt[base + i];
    ps[t] = s;
    __syncthreads();
    for (int d = 1; d < 256; d <<= 1) {
      int v = (t >= d) ? ps[t - d] : 0;
      __syncthreads();
      ps[t] += v;
      __syncthreads();
    }
    int run = ps[t] - s;
    for (int i = 0; i < 64; ++i) {
      off[base + i] = run; cur[base + i] = run;
      run += cnt[base + i];
    }
    return;
  }
  const int tid  = threadIdx.x;
  const int lane = tid & 63;
  const int wv   = tid >> 6;
  const int jb   = blockIdx.x << 4;
  const int c0   = lane & 15, kg = lane >> 4;
  const int sw   = c0 & 7;

  __shared__ __align__(16) float lbuf[2][4096];   // [buf][row*256 + unit16B*4]

  // staging: thread covers rows wv+4i (i=0..3), 16B-unit `lane` of each 1KB chunk
  const float* gsrc[4];
  int ldst[4];
  #pragma unroll
  for (int i = 0; i < 4; ++i) {
    int r = wv + (i << 2);
    gsrc[i] = W + (size_t)(jb + r) * 16384 + (size_t)((lane ^ (r & 7)) << 2);
    ldst[i] = ((r << 6) + lane) << 2;
  }

  const int it0 = blockIdx.x & 63;               // K start-phase rotation
  f32x4 z = {0.f,0.f,0.f,0.f};
  f32x4 acc[4] = {z,z,z,z};
  f32x4 P[4], Q[4];

  {   // prologue: stage chunk 0 directly; P <- chunk 1, Q <- chunk 2
    int kk0 = it0 << 8;
    #pragma unroll
    for (int i = 0; i < 4; ++i) {
      f32x4 v = __builtin_nontemporal_load((const f32x4*)(gsrc[i] + kk0));
      *(f32x4*)&lbuf[0][ldst[i]] = v;
    }
    int kk1 = ((it0 + 1) & 63) << 8;
    #pragma unroll
    for (int i = 0; i < 4; ++i)
      P[i] = __builtin_nontemporal_load((const f32x4*)(gsrc[i] + kk1));
    int kk2 = ((it0 + 2) & 63) << 8;
    #pragma unroll
    for (int i = 0; i < 4; ++i)
      Q[i] = __builtin_nontemporal_load((const f32x4*)(gsrc[i] + kk2));
  }
  __syncthreads();

  const bf16x8* xpb = ((const bf16x8*)xpk) + lane;

#define G1_COMPUTE(ITX) do {                                                 \
    int ktg0_ = ((ITX) + it0 & 63) << 3;                                     \
    const float* lb_ = lbuf[(ITX) & 1] + (c0 << 8);                          \
    _Pragma("unroll")                                                        \
    for (int kk = 0; kk < 2; ++kk) {                                         \
      int ktl_ = (wv << 1) | kk;                                             \
      int u0_ = (ktl_ << 3) + (kg << 1);                                     \
      f32x4 a0 = *(const f32x4*)(lb_ + ((u0_ ^ sw) << 2));                   \
      f32x4 a1 = *(const f32x4*)(lb_ + (((u0_ + 1) ^ sw) << 2));             \
      bf16x8 a = cvt8(a0, a1);                                               \
      const bf16x8* bp_ = xpb + (size_t)((ktg0_ + ktl_) << 2) * 64;          \
      acc[0] = __builtin_amdgcn_mfma_f32_16x16x32_bf16(a, bp_[0],   acc[0], 0,0,0); \
      acc[1] = __builtin_amdgcn_mfma_f32_16x16x32_bf16(a, bp_[64],  acc[1], 0,0,0); \
      acc[2] = __builtin_amdgcn_mfma_f32_16x16x32_bf16(a, bp_[128], acc[2], 0,0,0); \
      acc[3] = __builtin_amdgcn_mfma_f32_16x16x32_bf16(a, bp_[192], acc[3], 0,0,0); \
    }                                                                        \
  } while (0)

#define G1_BODY(ITX, R) do {                                                 \
    const int it_ = (ITX);                                                   \
    {                                                                        \
      float* lo_ = lbuf[(it_ + 1) & 1];                                      \
      _Pragma("unroll")                                                      \
      for (int i = 0; i < 4; ++i) *(f32x4*)&lo_[ldst[i]] = R[i];             \
    }                                                                        \
    if (it_ <= 60) {                                                         \
      int kk_ = ((it_ + 3 + it0) & 63) << 8;                                 \
      _Pragma("unroll")                                                      \
      for (int i = 0; i < 4; ++i)                                            \
        R[i] = __builtin_nontemporal_load((const f32x4*)(gsrc[i] + kk_));    \
    }                                                                        \
    G1_COMPUTE(it_);                                                         \
    __syncthreads();                                                         \
  } while (0)

  for (int i2 = 0; i2 < 31; ++i2) {
    G1_BODY(2 * i2,     P);
    G1_BODY(2 * i2 + 1, Q);
  }
  G1_BODY(62, P);
  G1_COMPUTE(63);                     // chunk 63 already staged in lbuf[1]
#undef G1_BODY
#undef G1_COMPUTE
  __syncthreads();

  // --- k-split combine + BN2 + leaky + adain1 (wave 0), LDS aliased ---
  float* lred = &lbuf[0][0];          // 3*16*64 = 3072 floats (lbuf[0] dead)
  float* h2t  = &lbuf[1][0];          // 16*68  = 1088 floats (after combine)
  if (wv) {
    float* rp = lred + ((wv - 1) << 10) + lane;
    #pragma unroll
    for (int nt = 0; nt < 4; ++nt)
      #pragma unroll
      for (int r = 0; r < 4; ++r) rp[((nt<<2)+r)<<6] = acc[nt][r];
  }
  __syncthreads();
  if (wv == 0) {
    float val[4][4];
    const float* rp = lred + lane;
    #pragma unroll
    for (int nt = 0; nt < 4; ++nt)
      #pragma unroll
      for (int r = 0; r < 4; ++r) {
        int idx = ((nt<<2)+r)<<6;
        val[nt][r] = acc[nt][r] + rp[idx] + rp[idx+1024] + rp[idx+2048];
      }
    #pragma unroll
    for (int r = 0; r < 4; ++r) {
      int jr = (kg << 2) + r;
      int j  = jb + jr;
      float tb = trs_b[j];
      float v0 = val[0][r]+tb, v1 = val[1][r]+tb, v2 = val[2][r]+tb, v3 = val[3][r]+tb;
      float s = red16(v0+v1+v2+v3);
      float q = red16(v0*v0+v1*v1+v2*v2+v3*v3);
      float mean = s * 0.015625f;
      float var  = q * 0.015625f - mean*mean;
      float inv  = rsqrtf(var + 1e-5f) * bn2_g[j];
      float bb   = bn2_b[j];
      v0 = lrelu((v0-mean)*inv + bb); v1 = lrelu((v1-mean)*inv + bb);
      v2 = lrelu((v2-mean)*inv + bb); v3 = lrelu((v3-mean)*inv + bb);
      s = red16(v0+v1+v2+v3);
      q = red16(v0*v0+v1*v1+v2*v2+v3*v3);
      mean = s * 0.015625f;
      var  = q * 0.015625f - mean*mean;
      float sd = sqrtf(fmaxf(var, 0.f) * (64.f/63.f));
      float id = 1.f / (sd + 1e-8f);
      float* hr = h2t + jr * 68;
      hr[c0]    = g1[c0]    * (v0-mean)*id + be1[c0];
      hr[c0+16] = g1[c0+16] * (v1-mean)*id + be1[c0+16];
      hr[c0+32] = g1[c0+32] * (v2-mean)*id + be1[c0+32];
      hr[c0+48] = g1[c0+48] * (v3-mean)*id + be1[c0+48];
    }
  }
  __syncthreads();

  // gemm2 on the LDS tile: H3 tile = h2t @ fc1_w.T + colstats
  const float* ha = h2t + c0 * 68 + (kg << 3);
  bf16x8 a0 = cvt8(*(const f32x4*)ha,        *(const f32x4*)(ha+4));
  bf16x8 a1 = cvt8(*(const f32x4*)(ha+32),   *(const f32x4*)(ha+36));
  const bf16x8* fpv = ((const bf16x8*)fc1pk) + lane;
  f32x4 acc2[4] = {z,z,z,z};
  #pragma unroll
  for (int q = 0; q < 4; ++q) {
    int nt = (wv << 2) | q;
    acc2[q] = __builtin_amdgcn_mfma_f32_16x16x32_bf16(a0, fpv[nt*64],      acc2[q], 0,0,0);
    acc2[q] = __builtin_amdgcn_mfma_f32_16x16x32_bf16(a1, fpv[(16+nt)*64], acc2[q], 0,0,0);
  }
  #pragma unroll
  for (int q = 0; q < 4; ++q) {
    int c = (((wv << 2) | q) << 4) + c0;
    float bias = fc1_b[c];
    float cs = 0.f, cq = 0.f;
    #pragma unroll
    for (int r = 0; r < 4; ++r) {
      float v = acc2[q][r] + bias;
      H3[(size_t)(jb + (kg<<2) + r) * 256 + c] = v;
      cs += v; cq += v*v;
    }
    cs += __shfl_xor(cs, 16); cs += __shfl_xor(cs, 32);
    cq += __shfl_xor(cq, 16); cq += __shfl_xor(cq, 32);
    if (kg == 0) { atomicAdd(&colsum[c], cs); atomicAdd(&colsq[c], cq); }
  }
}

// ---------------------------------------------------------------------------
// K2: fused BN1+leaky+adain2 -> xs(bf16) = H4 @ gat_w.T, a_s, a_d.
// Blocks 0..1023: GEMM (waves split K, LDS combine).
// Blocks 1024..2047: counting-sort scatter (overlapped; needs only scan+ei).
// ---------------------------------------------------------------------------
__global__ __launch_bounds__(256) void k_gemm3(
    const float* __restrict__ H3, const float* __restrict__ colsum,
    const float* __restrict__ colsq, const float* __restrict__ bn1_g,
    const float* __restrict__ bn1_b, const float* __restrict__ gb,
    const u16* __restrict__ gatpk,
    const float* __restrict__ att_s, const float* __restrict__ att_d,
    u16* __restrict__ xs, float* __restrict__ a_s, float* __restrict__ a_d,
    const int* __restrict__ src, const int* __restrict__ dstE,
    int* __restrict__ cur, int* __restrict__ ssrc)
{
  if (blockIdx.x >= 1024) {           // fused scatter: 1024 blocks
    int t = ((blockIdx.x - 1024) << 8) + threadIdx.x;
    #pragma unroll
    for (int i = 0; i < 4; ++i) {
      int e = t + i * 262144;
      int s = src[e], d = dstE[e];
      int p = atomicAdd(&cur[d], 1);
      ssrc[p] = s;
    }
    return;
  }
  const int lane = threadIdx.x & 63, wv = threadIdx.x >> 6;
  const int jb = blockIdx.x << 4;
  const int c0 = lane & 15, kg = lane >> 4;
  const int row = jb + c0;
  const int col0 = (wv << 6) + (kg << 3);         // + kk*32
  const float* g2  = gb + 128;
  const float* be2 = gb + 384;

  f32x4 w4[4];
  float ps = 0.f, pq = 0.f;
  #pragma unroll
  for (int kk = 0; kk < 2; ++kk) {
    #pragma unroll
    for (int h = 0; h < 2; ++h) {
      int c = col0 + kk*32 + h*4;
      f32x4 v  = *(const f32x4*)(H3 + (size_t)row*256 + c);
      f32x4 cm = *(const f32x4*)(colsum + c);
      f32x4 cq = *(const f32x4*)(colsq + c);
      f32x4 gg = *(const f32x4*)(bn1_g + c);
      f32x4 bb = *(const f32x4*)(bn1_b + c);
      f32x4 t;
      #pragma unroll
      for (int i = 0; i < 4; ++i) {
        float m  = cm[i] * (1.f/16384.f);
        float va = cq[i] * (1.f/16384.f) - m*m;
        float u  = (v[i]-m) * rsqrtf(va + 1e-5f) * gg[i] + bb[i];
        u = lrelu(u);
        t[i] = u; ps += u; pq += u*u;
      }
      w4[kk*2+h] = t;
    }
  }
  ps += __shfl_xor(ps, 16); ps += __shfl_xor(ps, 32);
  pq += __shfl_xor(pq, 16); pq += __shfl_xor(pq, 32);
  __shared__ float sps[64], sqs[64];
  if (kg == 0) { sps[(wv<<4) + c0] = ps; sqs[(wv<<4) + c0] = pq; }
  __syncthreads();
  float rs = sps[c0] + sps[16+c0] + sps[32+c0] + sps[48+c0];
  float rq = sqs[c0] + sqs[16+c0] + sqs[32+c0] + sqs[48+c0];
  float mean = rs * (1.f/256.f);
  float var  = rq * (1.f/256.f) - mean*mean;
  float sd   = sqrtf(fmaxf(var, 0.f) * (256.f/255.f));
  float id   = 1.f / (sd + 1e-8f);
  bf16x8 afr[2];
  #pragma unroll
  for (int kk = 0; kk < 2; ++kk) {
    f32x4 o[2];
    #pragma unroll
    for (int h = 0; h < 2; ++h) {
      int c = col0 + kk*32 + h*4;
      f32x4 ga = *(const f32x4*)(g2 + c);
      f32x4 bd = *(const f32x4*)(be2 + c);
      #pragma unroll
      for (int i = 0; i < 4; ++i) o[h][i] = ga[i]*(w4[kk*2+h][i]-mean)*id + bd[i];
    }
    afr[kk] = cvt8(o[0], o[1]);
  }
  const bf16x8* bpv = ((const bf16x8*)gatpk) + lane;
  f32x4 z = {0.f,0.f,0.f,0.f};
  f32x4 acc[4] = {z,z,z,z};
  #pragma unroll
  for (int kk = 0; kk < 2; ++kk) {
    int kt = (wv << 1) | kk;
    #pragma unroll
    for (int nt = 0; nt < 4; ++nt)
      acc[nt] = __builtin_amdgcn_mfma_f32_16x16x32_bf16(afr[kk], bpv[((kt<<2)+nt)*64], acc[nt], 0,0,0);
  }
  __shared__ float lred[3 * 16 * 64];
  if (wv) {
    float* rp = lred + ((wv - 1) << 10) + lane;
    #pragma unroll
    for (int nt = 0; nt < 4; ++nt)
      #pragma unroll
      for (int r = 0; r < 4; ++r) rp[((nt<<2)+r)<<6] = acc[nt][r];
  }
  __syncthreads();
  if (wv) return;
  float as0 = att_s[c0], as1 = att_s[c0+16], as2 = att_s[c0+32], as3 = att_s[c0+48];
  float ad0 = att_d[c0], ad1 = att_d[c0+16], ad2 = att_d[c0+32], ad3 = att_d[c0+48];
  const float* rp = lred + lane;
  #pragma unroll
  for (int r = 0; r < 4; ++r) {
    int j = jb + (kg << 2) + r;
    float v[4];
    #pragma unroll
    for (int nt = 0; nt < 4; ++nt) {
      int idx = ((nt<<2)+r)<<6;
      v[nt] = acc[nt][r] + rp[idx] + rp[idx+1024] + rp[idx+2048];
    }
    u16* op = xs + (size_t)j * 64 + c0;
    op[0]  = (u16)f2bf(v[0]);
    op[16] = (u16)f2bf(v[1]);
    op[32] = (u16)f2bf(v[2]);
    op[48] = (u16)f2bf(v[3]);
    float ss = red16(v[0]*as0 + v[1]*as1 + v[2]*as2 + v[3]*as3);
    float dd = red16(v[0]*ad0 + v[1]*ad1 + v[2]*ad2 + v[3]*ad3);
    if (c0 == 0) { a_s[j] = ss; a_d[j] = dd; }
  }
}

// K3: per-dst segment softmax + weighted gather (bf16 xs, 8 edges x 8 lanes
// x 16B per step) + leaky + adain3 -> d_out.
__global__ __launch_bounds__(256) void k_gat(
    const int* __restrict__ cnt, const int* __restrict__ off,
    const int* __restrict__ ssrc, const float* __restrict__ a_s,
    const float* __restrict__ a_d,
    const u16* __restrict__ xs, const float* __restrict__ gat_b,
    const float* __restrict__ g3, const float* __restrict__ be3,
    float* __restrict__ out)
{
  const int lane = threadIdx.x & 63, wv = threadIdx.x >> 6;
  const int j = (blockIdx.x << 2) | wv;
  const int n = cnt[j], beg = off[j];
  const int c8 = (lane & 7) << 3;     // feature base (8 features/lane)
  const int eq = lane >> 3;           // edge slot 0..7
  const float adj = a_d[j];
  float acc[8] = {0.f,0.f,0.f,0.f,0.f,0.f,0.f,0.f};
  float den = 0.f;
  if (n > 0) {
    for (int ch = 0; ch < n; ch += 64) {
      int k = ch + lane;
      bool ok = k < n;
      int   s = ok ? ssrc[beg + k] : 0;
      float p = ok ? __expf(lrelu(a_s[s] + adj)) : 0.f;
      den += p;
      int m = n - ch; if (m > 64) m = 64;
      int iters = (m + 7) >> 3;
      for (int i = 0; i < iters; ++i) {
        int idx = (i << 3) | eq;
        float pi = __shfl(p, idx);
        int   si = __shfl(s, idx);
        u16x8 hv = *(const u16x8*)(xs + (size_t)si * 64 + c8);
        #pragma unroll
        for (int t = 0; t < 8; ++t) acc[t] += pi * bf2f(hv[t]);
      }
    }
    den = red64(den);
    #pragma unroll
    for (int t = 0; t < 8; ++t) {
      acc[t] += __shfl_xor(acc[t], 8);
      acc[t] += __shfl_xor(acc[t], 16);
      acc[t] += __shfl_xor(acc[t], 32);
    }
    float rd = 1.f / den;
    #pragma unroll
    for (int t = 0; t < 8; ++t) acc[t] *= rd;
  }
  // bias + leaky; per-lane partial stats over its 8 features
  float vv[8];
  float s8 = 0.f, q8 = 0.f;
  #pragma unroll
  for (int t = 0; t < 8; ++t) {
    float v = lrelu(acc[t] + gat_b[c8 + t]);
    vv[t] = v; s8 += v; q8 += v * v;
  }
  // total over 64 features: butterfly across the 8 feature-groups
  s8 += __shfl_xor(s8, 1); s8 += __shfl_xor(s8, 2); s8 += __shfl_xor(s8, 4);
  q8 += __shfl_xor(q8, 1); q8 += __shfl_xor(q8, 2); q8 += __shfl_xor(q8, 4);
  float mean = s8 * (1.f/64.f);
  float var  = q8 * (1.f/64.f) - mean*mean;
  float sd   = sqrtf(fmaxf(var, 0.f) * (64.f/63.f));
  float id   = 1.f / (sd + 1e-8f);
  if (eq == 0) {
    f32x4 o0, o1;
    #pragma unroll
    for (int t = 0; t < 4; ++t) {
      o0[t] = g3[c8+t]   * (vv[t]  -mean)*id + be3[c8+t];
      o1[t] = g3[c8+4+t] * (vv[4+t]-mean)*id + be3[c8+4+t];
    }
    float* op = out + (size_t)j * 64 + c8;
    *(f32x4*)op       = o0;
    *(f32x4*)(op + 4) = o1;
  }
}

// ---------------------------------------------------------------------------
extern "C" void kernel_launch(void* const* d_in, const int* in_sizes, int n_in,
                              void* d_out, int out_size, void* d_ws, size_t ws_size,
                              hipStream_t stream) {
  (void)in_sizes; (void)n_in; (void)out_size; (void)ws_size;
  const float* x      = (const float*)d_in[0];
  const float* style  = (const float*)d_in[1];
  const int*   ei     = (const int*)d_in[2];
  const float* trs_w  = (const float*)d_in[3];
  const float* trs_b  = (const float*)d_in[4];
  const float* bn2_g  = (const float*)d_in[5];
  const float* bn2_b  = (const float*)d_in[6];
  const float* fc1_w  = (const float*)d_in[7];
  const float* fc1_b  = (const float*)d_in[8];
  const float* bn1_g  = (const float*)d_in[9];
  const float* bn1_b  = (const float*)d_in[10];
  const float* gat_w  = (const float*)d_in[11];
  const float* att_s  = (const float*)d_in[12];
  const float* att_d  = (const float*)d_in[13];
  const float* gat_b  = (const float*)d_in[14];
  const float* a1w1   = (const float*)d_in[15];
  const float* a1b1   = (const float*)d_in[16];
  const float* a1w2   = (const float*)d_in[17];
  const float* a1b2   = (const float*)d_in[18];
  const float* a2w1   = (const float*)d_in[19];
  const float* a2b1   = (const float*)d_in[20];
  const float* a2w2   = (const float*)d_in[21];
  const float* a2b2   = (const float*)d_in[22];
  const float* a3w1   = (const float*)d_in[23];
  const float* a3b1   = (const float*)d_in[24];
  const float* a3w2   = (const float*)d_in[25];
  const float* a3b2   = (const float*)d_in[26];

  char* ws = (char*)d_ws;
  u16*   xpk    = (u16*)(ws);                    // 2,097,152 B
  u16*   fc1pk  = (u16*)(ws + 2097152);          //    32,768 B
  u16*   gatpk  = (u16*)(ws + 2129920);          //    32,768 B
  float* gb     = (float*)(ws + 2162688);        //     3,072 B
  float* H3     = (float*)(ws + 6361088);        // 16,777,216 B
  u16*   xs     = (u16*)(ws + 39915520);         // 2,097,152 B (bf16)
  float* as_    = (float*)(ws + 44109824);       //    65,536 B
  float* ad_    = (float*)(ws + 44175360);       //    65,536 B
  float* colsum = (float*)(ws + 44240896);       //     1,024 B
  float* colsq  = (float*)(ws + 44241920);       //     1,024 B
  int*   cnt    = (int*)(ws + 44242944);         //    65,536 B
  int*   off    = (int*)(ws + 44308480);         //    65,536 B
  int*   cur    = (int*)(ws + 44374016);         //    65,536 B
  int*   ssrc   = (int*)(ws + 44439552);         // 4,194,304 B

  hipMemsetAsync(colsum, 0, 2048, stream);       // colsum + colsq
  hipMemsetAsync(cnt, 0, 65536, stream);

  k_prep<<<1555, 256, 0, stream>>>(x, style, fc1_w, gat_w,
      a1w1, a1b1, a1w2, a1b2, a2w1, a2b1, a2w2, a2b2, a3w1, a3b1, a3w2, a3b2,
      xpk, fc1pk, gatpk, gb, ei + NEDGE, cnt);
  k_gemm12<<<1025, 256, 0, stream>>>(trs_w, xpk, trs_b, bn2_g, bn2_b,
      gb, gb + 64, fc1pk, fc1_b, H3, colsum, colsq, cnt, off, cur);
  k_gemm3<<<2048, 256, 0, stream>>>(H3, colsum, colsq, bn1_g, bn1_b, gb,
      gatpk, att_s, att_d, xs, as_, ad_, ei, ei + NEDGE, cur, ssrc);
  k_gat<<<4096, 256, 0, stream>>>(cnt, off, ssrc, as_, ad_, xs, gat_b,
      gb + 640, gb + 704, (float*)d_out);
}